// Round 1
// baseline (90.392 us; speedup 1.0000x reference)
//
#include <hip/hip_runtime.h>

// Pooling_2D_density_3D: out[b,r,c] = sum_k mask[k,r]*mask[k,c]*X[b,cols[k,r],cols[k,c]]
// I=16, O=8, J=4, B=16 -> n_in=1024, n_out=256, K=81.
// cols/mask are deterministic constants; the 81 projectors decompose into 4
// closed-form terms (see derivation in session notes):
//   r = i1*32 + j1*4 + c1, c = i2*32 + j2*4 + c2
//   T0 (k=0, always):            X[row0+c1, col0+c2], row0=((2i1+1)*16+2j1+1)*4, col0=((2i2+1)*16+2j2+1)*4
//   T1 (k=1+8i+j, i1==i2&&j1==j2): X[rc1+c1, rc1+c2],  rc1=(32*i1+2*j1)*4
//   T2 (k=65+i,  i1==i2):         X[row2+c1, col2+c2], row2=(32*i1+2*j1+1)*4, col2=(32*i1+2*j2+1)*4
//   T3 (k=73+j,  j1==j2):         X[row3+c1, col3+c2], row3=((2i1+1)*16+2j1)*4, col3=((2i2+1)*16+2j1)*4
// Each thread computes one c2-quad (4 outputs) with float4 gathers.

__global__ __launch_bounds__(256) void pool_proj_kernel(const float* __restrict__ x,
                                                        float* __restrict__ out) {
    int q = blockIdx.x * blockDim.x + threadIdx.x;   // 0 .. 262143
    int b  = q >> 14;            // 16 batches
    int r1 = (q >> 6) & 255;     // output row
    int g2 = q & 63;             // (i2,j2) group; c2 handled by float4
    int i2 = g2 >> 3, j2 = g2 & 7;
    int i1 = r1 >> 5, j1 = (r1 >> 2) & 7, c1 = r1 & 3;

    const float* Xb = x + (size_t)b * 1024 * 1024;

    // T0: always present (projector 0 covers every row)
    int row0 = ((2 * i1 + 1) * 16 + (2 * j1 + 1)) * 4 + c1;
    int col0 = ((2 * i2 + 1) * 16 + (2 * j2 + 1)) * 4;
    float4 acc = *(const float4*)(Xb + (size_t)row0 * 1024 + col0);

    bool di = (i1 == i2);
    bool dj = (j1 == j2);

    if (di && dj) {  // T1: 4x4 diagonal-block projectors k=1..64
        int rc = (32 * i1 + 2 * j1) * 4;
        float4 v = *(const float4*)(Xb + (size_t)(rc + c1) * 1024 + rc);
        acc.x += v.x; acc.y += v.y; acc.z += v.z; acc.w += v.w;
    }
    if (di) {        // T2: k=65+i row-band projectors
        int row2 = (32 * i1 + 2 * j1 + 1) * 4 + c1;
        int col2 = (32 * i1 + 2 * j2 + 1) * 4;
        float4 v = *(const float4*)(Xb + (size_t)row2 * 1024 + col2);
        acc.x += v.x; acc.y += v.y; acc.z += v.z; acc.w += v.w;
    }
    if (dj) {        // T3: k=73+j column-band projectors
        int row3 = ((2 * i1 + 1) * 16 + 2 * j1) * 4 + c1;
        int col3 = ((2 * i2 + 1) * 16 + 2 * j1) * 4;
        float4 v = *(const float4*)(Xb + (size_t)row3 * 1024 + col3);
        acc.x += v.x; acc.y += v.y; acc.z += v.z; acc.w += v.w;
    }

    // out[b, r1, g2*4 .. g2*4+3]
    *(float4*)(out + (size_t)b * 65536 + (size_t)r1 * 256 + g2 * 4) = acc;
}

extern "C" void kernel_launch(void* const* d_in, const int* in_sizes, int n_in,
                              void* d_out, int out_size, void* d_ws, size_t ws_size,
                              hipStream_t stream) {
    const float* x = (const float*)d_in[0];   // (16, 1024, 1024) fp32
    float* out = (float*)d_out;               // (16, 256, 256) fp32
    // 16*256*64 = 262144 threads, each writes one float4
    dim3 grid(1024), block(256);
    hipLaunchKernelGGL(pool_proj_kernel, grid, block, 0, stream, x, out);
}